// Round 20
// baseline (92.829 us; speedup 1.0000x reference)
//
#include <hip/hip_runtime.h>
#include <hip/hip_bf16.h>

// out = softmax((X Wq + bq)(X Wk + bk)^T / 8) (X Wv + bv) Wo + bo
// All prune/straight-through ops in the reference are value-wise identity.
//
//   k_prep: fused {hs->bf16 A | W^T bf16 x4 | kh/vt pad zero}   (round-6 proven)
//   k_gemm: SMALL-BLOCK GEMM: 256 thr / 4 waves, tile 64x128, BK=32, 3-slot
//           single-barrier counted-vmcnt(3) K-loop. LDS 36KB -> 4 blocks/CU
//           co-resident = 4 independent barrier groups per CU.
//           (r19 bug fixed: B region starts at 2048 shorts within the 6144-
//            short slot; r19 used 4096 -> slot overflow + wrong read base.)
//   k_attn: flash attention, QBLK=128/KVBLK=128, 5 key-iters, one barrier per
//           iteration (round-18)

#define B_ 8
#define S_ 577
#define H_ 768
#define NH_ 12
#define HD_ 64
#define M_ (B_*S_)     /* 4616 */
#define MPAD 4736      /* 74*64 */
#define BH_ (B_*NH_)   /* 96 */
#define SKPAD 640      /* padded key count */
#define LTS 136        /* padded LDS row stride (Q/K epilogue rows) */
#define LTV 72         /* padded LDS row stride (V epilogue rows)  */

typedef __attribute__((ext_vector_type(8))) short short8;
typedef __attribute__((ext_vector_type(4))) short s16x4;
typedef __attribute__((ext_vector_type(4))) float f32x4;

__device__ inline unsigned short f2bf(float f){
    unsigned int u = __float_as_uint(f);
    u = u + 0x7fffu + ((u>>16)&1u);     // round-to-nearest-even
    return (unsigned short)(u>>16);
}

__device__ inline void gload_lds16(const short* g, short* l){
    __builtin_amdgcn_global_load_lds((const __attribute__((address_space(1))) void*)g,
                                     (__attribute__((address_space(3))) void*)l, 16, 0, 0);
}

// fused prep: blocks [0,1776) cvt | [1776,2352) wt | [2352,2733) pad
__global__ __launch_bounds__(256) void k_prep(
    const float* __restrict__ hs, short* __restrict__ abf,
    const float* __restrict__ Wq, const float* __restrict__ Wk,
    const float* __restrict__ Wv, const float* __restrict__ Wo,
    short* __restrict__ Tq, short* __restrict__ Tk,
    short* __restrict__ Tv, short* __restrict__ To,
    short* __restrict__ kh, short* __restrict__ vt)
{
    const int bid = blockIdx.x, t = threadIdx.x;
    if(bid < 1776){
        int i = bid*256 + t;
        if(bid >= 1731){ *(short8*)(abf + (size_t)i*8) = (short8){}; return; }
        const float4* p = (const float4*)(hs + (size_t)i*8);
        float4 a = p[0], b = p[1];
        short8 v;
        v[0]=(short)f2bf(a.x); v[1]=(short)f2bf(a.y); v[2]=(short)f2bf(a.z); v[3]=(short)f2bf(a.w);
        v[4]=(short)f2bf(b.x); v[5]=(short)f2bf(b.y); v[6]=(short)f2bf(b.z); v[7]=(short)f2bf(b.w);
        *(short8*)(abf + (size_t)i*8) = v;
    } else if(bid < 2352){
        int zidx = bid - 1776;
        int z = zidx & 3, rem = zidx >> 2;
        int kx = rem % 12, ny = rem / 12;
        const float* W = z==0?Wq: z==1?Wk: z==2?Wv:Wo;
        short*       T = z==0?Tq: z==1?Tk: z==2?Tv:To;
        __shared__ float lds[64][65];
        int k0 = kx*64, n0 = ny*64;
        for(int i=0;i<4;i++){
            int row = i*16 + (t>>4);
            int col = (t&15)*4;
            float4 v = *(const float4*)&W[(k0+row)*768 + n0 + col];
            lds[row][col]=v.x; lds[row][col+1]=v.y; lds[row][col+2]=v.z; lds[row][col+3]=v.w;
        }
        __syncthreads();
        for(int i=0;i<4;i++){
            int n = i*16 + (t>>4);
            int k4 = (t&15)*4;
            for(int j=0;j<4;j++)
                T[(n0+n)*768 + k0 + k4 + j] = (short)f2bf(lds[k4+j][n]);
        }
    } else {
        int tid = (bid-2352)*256 + t;
        short8 z = {};
        if(tid < 48384){
            int row_id = tid>>3, ch = tid&7;
            int bh = row_id/63, r = row_id - bh*63;
            *(short8*)&kh[((size_t)bh*SKPAD + 577 + r)*64 + ch*8] = z;
        } else if(tid < 97536){
            int j = tid - 48384;
            int row_id = j>>3, ch = j&7;
            int bh = row_id>>6, d = row_id&63;
            *(short8*)&vt[((size_t)bh*64 + d)*SKPAD + 576 + ch*8] = z;
        }
    }
}

// 64x128 tile GEMM, 256 threads / 4 waves (wave = 32x64), BK=32, 3-slot
// single-barrier counted-vmcnt(3) K-loop.  LDS 36KB -> 4 blocks/CU.
// slot layout (shorts): [0,2048) A 64x32 | [2048,6144) B 128x32
// mode 0: A[4736][768] @ Tqkv[2304][768]^T -> q/k/v ; mode 3: ctx@Wo+bo -> fp32
__global__ __launch_bounds__(256) void k_gemm(
    const short* __restrict__ A, const short* __restrict__ T,
    const float* __restrict__ b0, const float* __restrict__ b1, const float* __restrict__ b2,
    short* __restrict__ oq, short* __restrict__ ok, short* __restrict__ ovt,
    float* __restrict__ of, int mode, int NT)
{
    __shared__ short sh[18432];   // 36KB: 3 slots x 6144 shorts; epilogue fits
    const int t = threadIdx.x;

    const int nwg = gridDim.x;
    const int q8 = nwg>>3, r8 = nwg&7;
    const int xcd = blockIdx.x&7, cidx = blockIdx.x>>3;
    const int wg = (xcd<r8 ? xcd*(q8+1) : r8*(q8+1) + (xcd-r8)*q8) + cidx;
    const int mt = wg/NT, ntile = wg - mt*NT;
    const int m0 = mt*64, n0 = ntile*128;

    const int seg = (mode==3)? 0 : n0/768;
    const float* bias = (mode==3)? b0 : (seg==0?b0: seg==1?b1:b2);
    const int nlb = (mode==3)? n0 : n0 - seg*768;

    const int w = t>>6, lane = t&63, g = lane>>4, c = lane&15;
    const int wm = w>>1, wn = w&1;   // wave tile: rows wm*32.., cols wn*64..

    // staging (BK=32): thread t -> row t>>2, 16B-chunk t&3; source chunk
    // (t&3) ^ ((row>>1)&3) so LDS[row][ch] = G[row][ch ^ ((row>>1)&3)].
    // A: 1 chunk/thread (64 rows); B: 2 chunks/thread (rows r, r+64; same XOR
    // key since (64+r)>>1 adds 32 ≡ 0 mod 4).
    const int srow = t>>2, sch = t&3;
    const int sx = (sch ^ ((srow>>1)&3))*8;
    const short* gA  = A + (size_t)(m0 + srow)*768 + sx;
    const short* gB0 = T + (size_t)(n0 + srow)*768 + sx;
    const short* gB1 = T + (size_t)(n0 + 64 + srow)*768 + sx;
    const int dA  = srow*32 + sch*8;
    const int dB0 = 2048 + dA;
    const int dB1 = 2048 + (64+srow)*32 + sch*8;

    #define SLOT(k) (((k)%3)*6144)
    #define ISS(k) { gload_lds16(gA  + (k)*32, &sh[SLOT(k)+dA ]); \
                     gload_lds16(gB0 + (k)*32, &sh[SLOT(k)+dB0]); \
                     gload_lds16(gB1 + (k)*32, &sh[SLOT(k)+dB1]); }

    f32x4 acc[2][4] = {};

    // prologue: stage tiles 0,1; counted wait for tile 0
    ISS(0); ISS(1);
    asm volatile("s_waitcnt vmcnt(3)" ::: "memory");
    __builtin_amdgcn_s_barrier();
    asm volatile("" ::: "memory");

    for(int kt=0; kt<24; kt++){
        const short* LA = &sh[SLOT(kt)];
        const short* LB = LA + 2048;
        short8 af[2], bf[4];
        #pragma unroll
        for(int mi=0; mi<2; mi++){
            int row = wm*32 + mi*16 + c;
            af[mi] = *(const short8*)&LA[row*32 + ((g ^ ((row>>1)&3))<<3)];
        }
        #pragma unroll
        for(int ni=0; ni<4; ni++){
            int row = wn*64 + ni*16 + c;
            bf[ni] = *(const short8*)&LB[row*32 + ((g ^ ((row>>1)&3))<<3)];
        }
        if(kt<22) ISS(kt+2);
        asm volatile("s_waitcnt lgkmcnt(0)" ::: "memory");
        __builtin_amdgcn_s_setprio(1);
        #pragma unroll
        for(int mi=0; mi<2; mi++)
            #pragma unroll
            for(int ni=0; ni<4; ni++)
                acc[mi][ni] = __builtin_amdgcn_mfma_f32_16x16x32_bf16(af[mi], bf[ni], acc[mi][ni], 0,0,0);
        __builtin_amdgcn_s_setprio(0);
        if(kt<23){
            if(kt<22){ asm volatile("s_waitcnt vmcnt(3)" ::: "memory"); }
            else     { asm volatile("s_waitcnt vmcnt(0)" ::: "memory"); }
            __builtin_amdgcn_s_barrier();
            asm volatile("" ::: "memory");
        }
    }
    #undef SLOT
    #undef ISS

    if(mode==3){
        #pragma unroll
        for(int mi=0; mi<2; mi++) for(int ni=0; ni<4; ni++){
            #pragma unroll
            for(int r=0; r<4; r++){
                int m = m0 + wm*32 + mi*16 + g*4 + r;   // C/D: row=(lane>>4)*4+reg
                int n = n0 + wn*64 + ni*16 + c;         // C/D: col=lane&15
                if(m >= M_) continue;
                of[(size_t)m*768 + n] = acc[mi][ni][r] + bias[n];
            }
        }
        return;
    }

    __syncthreads();   // all reads of sh done before epilogue overwrite

    if(seg==2){
        // V: transposed [n 128][m 64], stride LTV
        #pragma unroll
        for(int mi=0;mi<2;mi++)
            #pragma unroll
            for(int ni=0;ni<4;ni++){
                int nl_ = wn*64 + ni*16 + c;
                float bv = bias[nlb + nl_];
                s16x4 pk;
                #pragma unroll
                for(int r=0;r<4;r++) pk[r] = (short)f2bf(acc[mi][ni][r] + bv);
                int ml0 = wm*32 + mi*16 + g*4;
                *(s16x4*)&sh[nl_*LTV + ml0] = pk;
            }
    } else {
        // Q/K: row-major [m 64][n 128], stride LTS
        #pragma unroll
        for(int mi=0;mi<2;mi++)
            #pragma unroll
            for(int ni=0;ni<4;ni++){
                int nl_ = wn*64 + ni*16 + c;
                float bv = bias[nlb + nl_];
                #pragma unroll
                for(int r=0;r<4;r++){
                    int ml = wm*32 + mi*16 + g*4 + r;
                    sh[ml*LTS + nl_] = (short)f2bf(acc[mi][ni][r] + bv);
                }
            }
    }
    __syncthreads();

    #pragma unroll
    for(int i=0;i<4;i++){
        int idx = i*256 + t;
        if(seg==2){
            int rp = idx>>3, ch = idx&7;        // 128 n-rows x 8 chunks (64 m)
            short8 v8 = *(const short8*)&sh[rp*LTV + ch*8];
            int nl = nlb + rp, hh = nl>>6, dd = nl&63;
            int mg = m0 + ch*8;
            if(mg < M_){
                int b0_ = mg/S_, s0 = mg - b0_*S_;
                if(s0+7 < S_ && mg+7 < M_){
                    *(short8*)&ovt[(((size_t)b0_*NH_+hh)*HD_+dd)*SKPAD + s0] = v8;
                } else {
                    for(int j=0;j<8;j++){
                        int m=mg+j;
                        if(m<M_){ int bj=m/S_, sj=m-bj*S_;
                            ovt[(((size_t)bj*NH_+hh)*HD_+dd)*SKPAD+sj]=v8[j]; }
                    }
                }
            }
        } else {
            int rp = idx>>4, ch = idx&15;       // 64 m-rows x 16 chunks (128 n)
            short8 v8 = *(const short8*)&sh[rp*LTS + ch*8];
            int m = m0 + rp;
            if(m < M_){
                int b0_ = m/S_, s0 = m - b0_*S_;
                int nl = nlb + ch*8, hh = nl>>6, dd = nl&63;
                if(seg==1) *(short8*)&ok[(((size_t)b0_*NH_+hh)*SKPAD + s0)*HD_ + dd] = v8;
                else       *(short8*)&oq[(((size_t)b0_*NH_+hh)*S_   + s0)*HD_ + dd] = v8;
            }
        }
    }
}

// flash attention: QBLK=128, KVBLK=128, 5 key-iterations, ONE barrier per
// iteration (round-18). 2-slot dbuf, per-qi softmax, exp2, MFMA row-sum, setprio.
__global__ __launch_bounds__(256) void k_attn(
    const short* __restrict__ qh, const short* __restrict__ kh, const short* __restrict__ vt,
    short* __restrict__ ctx)
{
    __shared__ short lK[2][128*64], lV[2][64*128], lP[4*2048];
    const int t = threadIdx.x;
    const int w = t>>6, lane = t&63, g = lane>>4, c = lane&15;
    const int bh = blockIdx.x, b = bh/NH_, h = bh%NH_;
    const int q0 = blockIdx.y*128;

    #pragma unroll
    for(int i=0;i<4;i++){
        int row = i*8 + (lane>>3);
        int e8 = (lane&7)*8;
        int s = q0 + w*32 + row;
        short8 v = {};
        if(s < S_) v = *(const short8*)&qh[((size_t)bh*S_ + s)*HD_ + e8];
        *(short8*)&lP[w*2048 + row*64 + (e8 ^ ((row&7)<<3))] = v;
    }
    short8 qf[2][2];
    #pragma unroll
    for(int qi=0; qi<2; qi++)
        #pragma unroll
        for(int ks=0; ks<2; ks++)
            qf[qi][ks] = *(const short8*)&lP[w*2048 + (qi*16+c)*64 + ((ks*32+g*8) ^ ((c&7)<<3))];

    short8 ones;
    #pragma unroll
    for(int j=0;j<8;j++) ones[j] = (short)0x3F80;    // bf16 1.0

    const short* pk[4]; const short* pv[4]; int dk[4], dv[4];
    #pragma unroll
    for(int i=0;i<4;i++){
        int id = i*256 + t;
        int krow = id>>3, kch = id&7;
        pk[i] = kh + ((size_t)bh*SKPAD + krow)*64 + (kch ^ (krow&7))*8;
        dk[i] = krow*64 + kch*8;
        int vd = id>>4, vch = id&15;
        pv[i] = vt + ((size_t)bh*64 + vd)*SKPAD + (vch ^ (vd&7))*8;
        dv[i] = vd*128 + vch*8;
    }
    #define STAGE(kt) { _Pragma("unroll") for(int i_=0;i_<4;i_++){           \
        gload_lds16(pk[i_] + (size_t)(kt)*8192, &lK[(kt)&1][dk[i_]]);        \
        gload_lds16(pv[i_] + (kt)*128,          &lV[(kt)&1][dv[i_]]); } }

    STAGE(0);

    float m_run[2][4], l_run[2][4];
    f32x4 O[2][4] = {};
    #pragma unroll
    for(int qi=0;qi<2;qi++)
        #pragma unroll
        for(int r=0;r<4;r++){ m_run[qi][r] = -3e38f; l_run[qi][r] = 0.f; }

    for(int kt=0; kt<5; kt++){
        asm volatile("s_waitcnt vmcnt(0)" ::: "memory");
        __builtin_amdgcn_s_barrier();
        asm volatile("" ::: "memory");
        if(kt<4) STAGE(kt+1);    // overwrites quiescent slot (kt+1)&1

        const short* LK = lK[kt&1]; const short* LV = lV[kt&1];

        #pragma unroll
        for(int qi=0; qi<2; qi++){
            float sv[8][4];
            #pragma unroll
            for(int nt=0; nt<8; nt++){
                int row = nt*16 + c;
                int rx = (row&7)<<3;
                short8 kf0 = *(const short8*)&LK[row*64 + ((g*8) ^ rx)];
                short8 kf1 = *(const short8*)&LK[row*64 + ((32+g*8) ^ rx)];
                __builtin_amdgcn_s_setprio(1);
                f32x4 sa = {};
                sa = __builtin_amdgcn_mfma_f32_16x16x32_bf16(qf[qi][0], kf0, sa, 0,0,0);
                sa = __builtin_amdgcn_mfma_f32_16x16x32_bf16(qf[qi][1], kf1, sa, 0,0,0);
                __builtin_amdgcn_s_setprio(0);
                #pragma unroll
                for(int r=0;r<4;r++) sv[nt][r] = sa[r]*0.18033688011f;  // /8 * log2(e)
            }
            if(kt==4){
                #pragma unroll
                for(int nt=0; nt<8; nt++){
                    int key = 512 + nt*16 + c;
                    if(key >= S_){
                        #pragma unroll
                        for(int r=0;r<4;r++) sv[nt][r] = -3e38f;
                    }
                }
            }
            float fac[4];
            #pragma unroll
            for(int r=0;r<4;r++){
                float mx = sv[0][r];
                #pragma unroll
                for(int nt=1;nt<8;nt++) mx = fmaxf(mx, sv[nt][r]);
                for(int off=1; off<16; off<<=1) mx = fmaxf(mx, __shfl_xor(mx, off));
                float nm = fmaxf(m_run[qi][r], mx);
                fac[r] = __builtin_amdgcn_exp2f(m_run[qi][r] - nm);
                m_run[qi][r] = nm;
            }
            #pragma unroll
            for(int nt=0; nt<8; nt++)
                #pragma unroll
                for(int r=0;r<4;r++){
                    float p = __builtin_amdgcn_exp2f(sv[nt][r] - m_run[qi][r]);
                    int prow = g*4 + r;
                    lP[w*2048 + prow*128 + ((nt*16 + c) ^ ((prow&7)<<3))] = (short)f2bf(p);
                }
            short8 pf[4];
            #pragma unroll
            for(int ks=0; ks<4; ks++)
                pf[ks] = *(const short8*)&lP[w*2048 + c*128 + ((ks*32+g*8) ^ ((c&7)<<3))];
            __builtin_amdgcn_s_setprio(1);
            f32x4 rs = {};
            #pragma unroll
            for(int ks=0; ks<4; ks++)
                rs = __builtin_amdgcn_mfma_f32_16x16x32_bf16(pf[ks], ones, rs, 0,0,0);
            __builtin_amdgcn_s_setprio(0);
            #pragma unroll
            for(int r=0;r<4;r++) l_run[qi][r] = l_run[qi][r]*fac[r] + rs[r];
            #pragma unroll
            for(int nt=0;nt<4;nt++)
                #pragma unroll
                for(int r=0;r<4;r++) O[qi][nt][r] *= fac[r];

            __builtin_amdgcn_s_setprio(1);
            #pragma unroll
            for(int nt=0; nt<4; nt++){
                int vrow = nt*16 + c;
                int rx = (vrow&7)<<3;
                #pragma unroll
                for(int ks=0; ks<4; ks++){
                    short8 vf = *(const short8*)&LV[vrow*128 + ((ks*32+g*8) ^ rx)];
                    O[qi][nt] = __builtin_amdgcn_mfma_f32_16x16x32_bf16(pf[ks], vf, O[qi][nt], 0,0,0);
                }
            }
            __builtin_amdgcn_s_setprio(0);
        }
    }
    #undef STAGE

    #pragma unroll
    for(int qi=0; qi<2; qi++)
        #pragma unroll
        for(int nt=0; nt<4; nt++)
            #pragma unroll
            for(int r=0;r<4;r++){
                int s = q0 + w*32 + qi*16 + g*4 + r;
                if(s < S_){
                    float val = O[qi][nt][r] / l_run[qi][r];
                    ctx[((size_t)b*S_ + s)*H_ + h*HD_ + nt*16 + c] = (short)f2bf(val);
                }
            }
}

extern "C" void kernel_launch(void* const* d_in, const int* in_sizes, int n_in,
                              void* d_out, int out_size, void* d_ws, size_t ws_size,
                              hipStream_t stream)
{
    const float* hs = (const float*)d_in[0];
    const float* Wq = (const float*)d_in[1];
    const float* bq = (const float*)d_in[2];
    const float* Wk = (const float*)d_in[3];
    const float* bk = (const float*)d_in[4];
    const float* Wv = (const float*)d_in[5];
    const float* bv = (const float*)d_in[6];
    const float* Wo = (const float*)d_in[7];
    const float* bo = (const float*)d_in[8];
    float* out = (float*)d_out;

    char* ws = (char*)d_ws;
    short* abf = (short*)(ws);
    short* ctx = abf;                               // reuse after QKV GEMM
    short* wqt = (short*)(ws + 7274496);
    short* wkt = (short*)(ws + 7274496 + 1179648);
    short* wvt = (short*)(ws + 7274496 + 2*1179648);
    short* wot = (short*)(ws + 7274496 + 3*1179648);
    short* qh  = (short*)(ws + 11993088);
    short* kh  = (short*)(ws + 19083264);
    short* vt  = (short*)(ws + 26947584);
    // total: 34,811,904 B

    k_prep<<<2733, 256, 0, stream>>>(hs, abf, Wq,Wk,Wv,Wo, wqt,wkt,wvt,wot, kh, vt);
    k_gemm<<<1332, 256, 0, stream>>>(abf, wqt, bq,bk,bv, qh,kh,vt, nullptr, 0, 18);
    k_attn<<<dim3(96,5), 256, 0, stream>>>(qh, kh, vt, ctx);
    k_gemm<<<444, 256, 0, stream>>>(ctx, wot, bo,bo,bo, nullptr,nullptr,nullptr, out, 3, 6);
}

// Round 21
// 83.547 us; speedup vs baseline: 1.1111x; 1.1111x over previous
//
#include <hip/hip_runtime.h>
#include <hip/hip_bf16.h>

// out = softmax((X Wq + bq)(X Wk + bk)^T / 8) (X Wv + bv) Wo + bo
// All prune/straight-through ops in the reference are value-wise identity.
//
//   k_prep: fused {hs->bf16 A | W^T bf16 x4 | kh/vt pad zero}   (round-6 proven)
//   k_gemm: 128x128 tile, 512 thr / 8 waves, BK=32, THREE LDS slots (48KB),
//           ONE barrier per K-step, counted vmcnt(2)             (round-17 proven)
//   k_attn: flash attention, QBLK=128/KVBLK=128, 5 key-iters, ONE barrier per
//           iteration: {vmcnt(0); barrier; STAGE(kt+1); compute} (round-18 proven)
//
// Best measured configuration: 83.58 us (round 18).

#define B_ 8
#define S_ 577
#define H_ 768
#define NH_ 12
#define HD_ 64
#define M_ (B_*S_)     /* 4616 */
#define MPAD 4736
#define BH_ (B_*NH_)   /* 96 */
#define SKPAD 640      /* padded key count */
#define LTS 136        /* padded LDS row stride (shorts) for epilogue tile */

typedef __attribute__((ext_vector_type(8))) short short8;
typedef __attribute__((ext_vector_type(4))) short s16x4;
typedef __attribute__((ext_vector_type(4))) float f32x4;

__device__ inline unsigned short f2bf(float f){
    unsigned int u = __float_as_uint(f);
    u = u + 0x7fffu + ((u>>16)&1u);     // round-to-nearest-even
    return (unsigned short)(u>>16);
}

__device__ inline void gload_lds16(const short* g, short* l){
    __builtin_amdgcn_global_load_lds((const __attribute__((address_space(1))) void*)g,
                                     (__attribute__((address_space(3))) void*)l, 16, 0, 0);
}

// fused prep: blocks [0,1776) cvt | [1776,2352) wt | [2352,2733) pad
__global__ __launch_bounds__(256) void k_prep(
    const float* __restrict__ hs, short* __restrict__ abf,
    const float* __restrict__ Wq, const float* __restrict__ Wk,
    const float* __restrict__ Wv, const float* __restrict__ Wo,
    short* __restrict__ Tq, short* __restrict__ Tk,
    short* __restrict__ Tv, short* __restrict__ To,
    short* __restrict__ kh, short* __restrict__ vt)
{
    const int bid = blockIdx.x, t = threadIdx.x;
    if(bid < 1776){
        int i = bid*256 + t;
        if(bid >= 1731){ *(short8*)(abf + (size_t)i*8) = (short8){}; return; }
        const float4* p = (const float4*)(hs + (size_t)i*8);
        float4 a = p[0], b = p[1];
        short8 v;
        v[0]=(short)f2bf(a.x); v[1]=(short)f2bf(a.y); v[2]=(short)f2bf(a.z); v[3]=(short)f2bf(a.w);
        v[4]=(short)f2bf(b.x); v[5]=(short)f2bf(b.y); v[6]=(short)f2bf(b.z); v[7]=(short)f2bf(b.w);
        *(short8*)(abf + (size_t)i*8) = v;
    } else if(bid < 2352){
        int zidx = bid - 1776;
        int z = zidx & 3, rem = zidx >> 2;
        int kx = rem % 12, ny = rem / 12;
        const float* W = z==0?Wq: z==1?Wk: z==2?Wv:Wo;
        short*       T = z==0?Tq: z==1?Tk: z==2?Tv:To;
        __shared__ float lds[64][65];
        int k0 = kx*64, n0 = ny*64;
        for(int i=0;i<4;i++){
            int row = i*16 + (t>>4);
            int col = (t&15)*4;
            float4 v = *(const float4*)&W[(k0+row)*768 + n0 + col];
            lds[row][col]=v.x; lds[row][col+1]=v.y; lds[row][col+2]=v.z; lds[row][col+3]=v.w;
        }
        __syncthreads();
        for(int i=0;i<4;i++){
            int n = i*16 + (t>>4);
            int k4 = (t&15)*4;
            for(int j=0;j<4;j++)
                T[(n0+n)*768 + k0 + k4 + j] = (short)f2bf(lds[k4+j][n]);
        }
    } else {
        int tid = (bid-2352)*256 + t;
        short8 z = {};
        if(tid < 48384){
            int row_id = tid>>3, ch = tid&7;
            int bh = row_id/63, r = row_id - bh*63;
            *(short8*)&kh[((size_t)bh*SKPAD + 577 + r)*64 + ch*8] = z;
        } else if(tid < 97536){
            int j = tid - 48384;
            int row_id = j>>3, ch = j&7;
            int bh = row_id>>6, d = row_id&63;
            *(short8*)&vt[((size_t)bh*64 + d)*SKPAD + 576 + ch*8] = z;
        }
    }
}

// 128x128 tile GEMM, 512 threads / 8 waves, BK=32, 3-slot single-barrier K-loop.
// mode 0: A[4736][768] @ Tqkv[2304][768]^T -> q/k/v ; mode 3: ctx@Wo+bo -> fp32
__global__ __launch_bounds__(512) void k_gemm(
    const short* __restrict__ A, const short* __restrict__ T,
    const float* __restrict__ b0, const float* __restrict__ b1, const float* __restrict__ b2,
    short* __restrict__ oq, short* __restrict__ ok, short* __restrict__ ovt,
    float* __restrict__ of, int mode, int NT)
{
    __shared__ short sh[24576];            // 48KB: 3 slots x (A 8KB | B 8KB); epi 34816B fits
    const int t = threadIdx.x;

    const int nwg = gridDim.x;
    const int q8 = nwg>>3, r8 = nwg&7;
    const int xcd = blockIdx.x&7, cidx = blockIdx.x>>3;
    const int wg = (xcd<r8 ? xcd*(q8+1) : r8*(q8+1) + (xcd-r8)*q8) + cidx;
    const int mt = wg/NT, ntile = wg - mt*NT;
    const int m0 = mt*128, n0 = ntile*128;

    const int seg = (mode==3)? 0 : n0/768;
    const float* bias = (mode==3)? b0 : (seg==0?b0: seg==1?b1:b2);
    const int nlb = (mode==3)? n0 : n0 - seg*768;

    const int w = t>>6, lane = t&63, g = lane>>4, c = lane&15;
    const int wm = w>>1, wn = w&1;

    // staging (BK=32): thread t covers row t>>2, 16B-chunk t&3; source chunk
    // (t&3) ^ ((row>>1)&3) so LDS[row][ch] = G[row][ch ^ ((row>>1)&3)]
    const int srow = t>>2, sch = t&3;
    const short* gA = A + (size_t)(m0 + srow)*768 + (sch ^ ((srow>>1)&3))*8;
    const short* gB = T + (size_t)(n0 + srow)*768 + (sch ^ ((srow>>1)&3))*8;
    const int dA = srow*32 + sch*8;
    const int dB = 4096 + dA;

    #define SLOT(k) (((k)%3)*8192)
    #define ISS(k) { gload_lds16(gA + (k)*32, &sh[SLOT(k)+dA]); \
                     gload_lds16(gB + (k)*32, &sh[SLOT(k)+dB]); }

    f32x4 acc[2][4] = {};

    // prologue: stage tiles 0,1; counted wait for tile 0
    ISS(0); ISS(1);
    asm volatile("s_waitcnt vmcnt(2)" ::: "memory");
    __builtin_amdgcn_s_barrier();
    asm volatile("" ::: "memory");

    for(int kt=0; kt<24; kt++){
        const short* LA = &sh[SLOT(kt)];
        const short* LB = LA + 4096;
        short8 af[2], bf[4];
        #pragma unroll
        for(int mi=0; mi<2; mi++){
            int row = wm*32 + mi*16 + c;
            af[mi] = *(const short8*)&LA[row*32 + ((g ^ ((row>>1)&3))<<3)];
        }
        #pragma unroll
        for(int ni=0; ni<4; ni++){
            int row = wn*64 + ni*16 + c;
            bf[ni] = *(const short8*)&LB[row*32 + ((g ^ ((row>>1)&3))<<3)];
        }
        if(kt<22) ISS(kt+2);
        asm volatile("s_waitcnt lgkmcnt(0)" ::: "memory");
        __builtin_amdgcn_s_setprio(1);
        #pragma unroll
        for(int mi=0; mi<2; mi++)
            #pragma unroll
            for(int ni=0; ni<4; ni++)
                acc[mi][ni] = __builtin_amdgcn_mfma_f32_16x16x32_bf16(af[mi], bf[ni], acc[mi][ni], 0,0,0);
        __builtin_amdgcn_s_setprio(0);
        if(kt<23){
            if(kt<22){ asm volatile("s_waitcnt vmcnt(2)" ::: "memory"); }
            else     { asm volatile("s_waitcnt vmcnt(0)" ::: "memory"); }
            __builtin_amdgcn_s_barrier();
            asm volatile("" ::: "memory");
        }
    }
    #undef SLOT
    #undef ISS

    if(mode==3){
        #pragma unroll
        for(int mi=0; mi<2; mi++) for(int ni=0; ni<4; ni++){
            #pragma unroll
            for(int r=0; r<4; r++){
                int m = m0 + wm*32 + mi*16 + g*4 + r;   // C/D: row=(lane>>4)*4+reg
                int n = n0 + wn*64 + ni*16 + c;         // C/D: col=lane&15
                if(m >= M_) continue;
                of[(size_t)m*768 + n] = acc[mi][ni][r] + bias[n];
            }
        }
        return;
    }

    __syncthreads();   // all reads of sh done before epilogue overwrite

    if(seg==2){
        #pragma unroll
        for(int mi=0;mi<2;mi++)
            #pragma unroll
            for(int ni=0;ni<4;ni++){
                int nl_ = wn*64 + ni*16 + c;
                float bv = bias[nlb + nl_];
                s16x4 pk;
                #pragma unroll
                for(int r=0;r<4;r++) pk[r] = (short)f2bf(acc[mi][ni][r] + bv);
                int ml0 = wm*32 + mi*16 + g*4;
                *(s16x4*)&sh[nl_*LTS + ml0] = pk;       // transposed: [n][m]
            }
    } else {
        #pragma unroll
        for(int mi=0;mi<2;mi++)
            #pragma unroll
            for(int ni=0;ni<4;ni++){
                int nl_ = wn*64 + ni*16 + c;
                float bv = bias[nlb + nl_];
                #pragma unroll
                for(int r=0;r<4;r++){
                    int ml = wm*32 + mi*16 + g*4 + r;
                    sh[ml*LTS + nl_] = (short)f2bf(acc[mi][ni][r] + bv);
                }
            }
    }
    __syncthreads();

    #pragma unroll
    for(int i=0;i<4;i++){
        int idx = i*512 + t;
        int rp = idx>>4, ch = idx&15;
        short8 v8 = *(const short8*)&sh[rp*LTS + ch*8];
        if(seg==2){
            int nl = nlb + rp, hh = nl>>6, dd = nl&63;
            int mg = m0 + ch*8;
            if(mg < M_){
                int b0_ = mg/S_, s0 = mg - b0_*S_;
                if(s0+7 < S_ && mg+7 < M_){
                    *(short8*)&ovt[(((size_t)b0_*NH_+hh)*HD_+dd)*SKPAD + s0] = v8;
                } else {
                    for(int j=0;j<8;j++){
                        int m=mg+j;
                        if(m<M_){ int bj=m/S_, sj=m-bj*S_;
                            ovt[(((size_t)bj*NH_+hh)*HD_+dd)*SKPAD+sj]=v8[j]; }
                    }
                }
            }
        } else {
            int m = m0 + rp;
            if(m < M_){
                int b0_ = m/S_, s0 = m - b0_*S_;
                int nl = nlb + ch*8, hh = nl>>6, dd = nl&63;
                if(seg==1) *(short8*)&ok[(((size_t)b0_*NH_+hh)*SKPAD + s0)*HD_ + dd] = v8;
                else       *(short8*)&oq[(((size_t)b0_*NH_+hh)*S_   + s0)*HD_ + dd] = v8;
            }
        }
    }
}

// flash attention: QBLK=128, KVBLK=128, 5 key-iterations, ONE barrier per
// iteration ({vmcnt(0); barrier; STAGE(kt+1); compute} - end barrier redundant
// via MFMA data-dependence). 2-slot dbuf, per-qi softmax, exp2, MFMA row-sum,
// setprio.
__global__ __launch_bounds__(256) void k_attn(
    const short* __restrict__ qh, const short* __restrict__ kh, const short* __restrict__ vt,
    short* __restrict__ ctx)
{
    __shared__ short lK[2][128*64], lV[2][64*128], lP[4*2048];
    const int t = threadIdx.x;
    const int w = t>>6, lane = t&63, g = lane>>4, c = lane&15;
    const int bh = blockIdx.x, b = bh/NH_, h = bh%NH_;
    const int q0 = blockIdx.y*128;

    // per-wave Q staging (32 rows) into own lP region, then frags to regs
    #pragma unroll
    for(int i=0;i<4;i++){
        int row = i*8 + (lane>>3);
        int e8 = (lane&7)*8;
        int s = q0 + w*32 + row;
        short8 v = {};
        if(s < S_) v = *(const short8*)&qh[((size_t)bh*S_ + s)*HD_ + e8];
        *(short8*)&lP[w*2048 + row*64 + (e8 ^ ((row&7)<<3))] = v;
    }
    short8 qf[2][2];
    #pragma unroll
    for(int qi=0; qi<2; qi++)
        #pragma unroll
        for(int ks=0; ks<2; ks++)
            qf[qi][ks] = *(const short8*)&lP[w*2048 + (qi*16+c)*64 + ((ks*32+g*8) ^ ((c&7)<<3))];

    short8 ones;
    #pragma unroll
    for(int j=0;j<8;j++) ones[j] = (short)0x3F80;    // bf16 1.0

    // staging maps (KVBLK=128): 4 K-chunks + 4 V-chunks per thread per tile
    const short* pk[4]; const short* pv[4]; int dk[4], dv[4];
    #pragma unroll
    for(int i=0;i<4;i++){
        int id = i*256 + t;
        int krow = id>>3, kch = id&7;            // 128 rows x 8 chunks
        pk[i] = kh + ((size_t)bh*SKPAD + krow)*64 + (kch ^ (krow&7))*8;
        dk[i] = krow*64 + kch*8;
        int vd = id>>4, vch = id&15;             // 64 d-rows x 16 chunks
        pv[i] = vt + ((size_t)bh*64 + vd)*SKPAD + (vch ^ (vd&7))*8;
        dv[i] = vd*128 + vch*8;
    }
    #define STAGE(kt) { _Pragma("unroll") for(int i_=0;i_<4;i_++){           \
        gload_lds16(pk[i_] + (size_t)(kt)*8192, &lK[(kt)&1][dk[i_]]);        \
        gload_lds16(pv[i_] + (kt)*128,          &lV[(kt)&1][dv[i_]]); } }

    STAGE(0);

    float m_run[2][4], l_run[2][4];
    f32x4 O[2][4] = {};
    #pragma unroll
    for(int qi=0;qi<2;qi++)
        #pragma unroll
        for(int r=0;r<4;r++){ m_run[qi][r] = -3e38f; l_run[qi][r] = 0.f; }

    for(int kt=0; kt<5; kt++){
        asm volatile("s_waitcnt vmcnt(0)" ::: "memory");
        __builtin_amdgcn_s_barrier();
        asm volatile("" ::: "memory");
        if(kt<4) STAGE(kt+1);    // overwrites quiescent slot (kt+1)&1

        const short* LK = lK[kt&1]; const short* LV = lV[kt&1];

        #pragma unroll
        for(int qi=0; qi<2; qi++){
            float sv[8][4];
            #pragma unroll
            for(int nt=0; nt<8; nt++){
                int row = nt*16 + c;
                int rx = (row&7)<<3;
                short8 kf0 = *(const short8*)&LK[row*64 + ((g*8) ^ rx)];
                short8 kf1 = *(const short8*)&LK[row*64 + ((32+g*8) ^ rx)];
                __builtin_amdgcn_s_setprio(1);
                f32x4 sa = {};
                sa = __builtin_amdgcn_mfma_f32_16x16x32_bf16(qf[qi][0], kf0, sa, 0,0,0);
                sa = __builtin_amdgcn_mfma_f32_16x16x32_bf16(qf[qi][1], kf1, sa, 0,0,0);
                __builtin_amdgcn_s_setprio(0);
                #pragma unroll
                for(int r=0;r<4;r++) sv[nt][r] = sa[r]*0.18033688011f;  // /8 * log2(e)
            }
            if(kt==4){
                #pragma unroll
                for(int nt=0; nt<8; nt++){
                    int key = 512 + nt*16 + c;
                    if(key >= S_){
                        #pragma unroll
                        for(int r=0;r<4;r++) sv[nt][r] = -3e38f;
                    }
                }
            }
            float fac[4];
            #pragma unroll
            for(int r=0;r<4;r++){
                float mx = sv[0][r];
                #pragma unroll
                for(int nt=1;nt<8;nt++) mx = fmaxf(mx, sv[nt][r]);
                for(int off=1; off<16; off<<=1) mx = fmaxf(mx, __shfl_xor(mx, off));
                float nm = fmaxf(m_run[qi][r], mx);
                fac[r] = __builtin_amdgcn_exp2f(m_run[qi][r] - nm);
                m_run[qi][r] = nm;
            }
            #pragma unroll
            for(int nt=0; nt<8; nt++)
                #pragma unroll
                for(int r=0;r<4;r++){
                    float p = __builtin_amdgcn_exp2f(sv[nt][r] - m_run[qi][r]);
                    int prow = g*4 + r;
                    lP[w*2048 + prow*128 + ((nt*16 + c) ^ ((prow&7)<<3))] = (short)f2bf(p);
                }
            short8 pf[4];
            #pragma unroll
            for(int ks=0; ks<4; ks++)
                pf[ks] = *(const short8*)&lP[w*2048 + c*128 + ((ks*32+g*8) ^ ((c&7)<<3))];
            __builtin_amdgcn_s_setprio(1);
            f32x4 rs = {};
            #pragma unroll
            for(int ks=0; ks<4; ks++)
                rs = __builtin_amdgcn_mfma_f32_16x16x32_bf16(pf[ks], ones, rs, 0,0,0);
            __builtin_amdgcn_s_setprio(0);
            #pragma unroll
            for(int r=0;r<4;r++) l_run[qi][r] = l_run[qi][r]*fac[r] + rs[r];
            #pragma unroll
            for(int nt=0;nt<4;nt++)
                #pragma unroll
                for(int r=0;r<4;r++) O[qi][nt][r] *= fac[r];

            __builtin_amdgcn_s_setprio(1);
            #pragma unroll
            for(int nt=0; nt<4; nt++){
                int vrow = nt*16 + c;
                int rx = (vrow&7)<<3;
                #pragma unroll
                for(int ks=0; ks<4; ks++){
                    short8 vf = *(const short8*)&LV[vrow*128 + ((ks*32+g*8) ^ rx)];
                    O[qi][nt] = __builtin_amdgcn_mfma_f32_16x16x32_bf16(pf[ks], vf, O[qi][nt], 0,0,0);
                }
            }
            __builtin_amdgcn_s_setprio(0);
        }
    }
    #undef STAGE

    #pragma unroll
    for(int qi=0; qi<2; qi++)
        #pragma unroll
        for(int nt=0; nt<4; nt++)
            #pragma unroll
            for(int r=0;r<4;r++){
                int s = q0 + w*32 + qi*16 + g*4 + r;
                if(s < S_){
                    float val = O[qi][nt][r] / l_run[qi][r];
                    ctx[((size_t)b*S_ + s)*H_ + h*HD_ + nt*16 + c] = (short)f2bf(val);
                }
            }
}

extern "C" void kernel_launch(void* const* d_in, const int* in_sizes, int n_in,
                              void* d_out, int out_size, void* d_ws, size_t ws_size,
                              hipStream_t stream)
{
    const float* hs = (const float*)d_in[0];
    const float* Wq = (const float*)d_in[1];
    const float* bq = (const float*)d_in[2];
    const float* Wk = (const float*)d_in[3];
    const float* bk = (const float*)d_in[4];
    const float* Wv = (const float*)d_in[5];
    const float* bv = (const float*)d_in[6];
    const float* Wo = (const float*)d_in[7];
    const float* bo = (const float*)d_in[8];
    float* out = (float*)d_out;

    char* ws = (char*)d_ws;
    short* abf = (short*)(ws);
    short* ctx = abf;                               // reuse after QKV GEMM
    short* wqt = (short*)(ws + 7274496);
    short* wkt = (short*)(ws + 7274496 + 1179648);
    short* wvt = (short*)(ws + 7274496 + 2*1179648);
    short* wot = (short*)(ws + 7274496 + 3*1179648);
    short* qh  = (short*)(ws + 11993088);
    short* kh  = (short*)(ws + 19083264);
    short* vt  = (short*)(ws + 26947584);
    // total: 34,811,904 B

    k_prep<<<2733, 256, 0, stream>>>(hs, abf, Wq,Wk,Wv,Wo, wqt,wkt,wvt,wot, kh, vt);
    k_gemm<<<666, 512, 0, stream>>>(abf, wqt, bq,bk,bv, qh,kh,vt, nullptr, 0, 18);
    k_attn<<<dim3(96,5), 256, 0, stream>>>(qh, kh, vt, ctx);
    k_gemm<<<222, 512, 0, stream>>>(ctx, wot, bo,bo,bo, nullptr,nullptr,nullptr, out, 3, 6);
}